// Round 6
// baseline (202.407 us; speedup 1.0000x reference)
//
#include <hip/hip_runtime.h>
#include <cfloat>
#include <cstdint>

#define N_GT 20000
#define N_T 50
#define NPA 8000          // N_POS * ALPHA
#define N_POS 2000
#define KSTEPS 625        // N_GT / 32
#define KTILE 32          // k rows per LDS tile
#define PBLK 256          // p columns per block
#define NS 8              // split-K slices (32 x 8 = 256 blocks = 1/CU)
#define SCH 2500          // softmax chunk (8 chunks per row)

typedef __attribute__((ext_vector_type(8))) short short8;
typedef __attribute__((ext_vector_type(4))) float f32x4;

// ---------------- block reduction helpers ----------------
__device__ __forceinline__ float wave_sum(float v) {
#pragma unroll
    for (int o = 32; o > 0; o >>= 1) v += __shfl_down(v, o, 64);
    return v;
}
__device__ float block_sum(float v, float* red) {
    int lane = threadIdx.x & 63, wid = threadIdx.x >> 6, nw = blockDim.x >> 6;
    v = wave_sum(v);
    __syncthreads();
    if (lane == 0) red[wid] = v;
    __syncthreads();
    if (wid == 0) {
        float x = (lane < nw) ? red[lane] : 0.f;
        x = wave_sum(x);
        if (lane == 0) red[0] = x;
    }
    __syncthreads();
    return red[0];
}

// ---------------- softmax pass 1: per-chunk sum of exp ----------------
__global__ __launch_bounds__(256) void softmax_sum_kernel(
    const float* __restrict__ fq, float* __restrict__ rowsum) {
    __shared__ float red[8];
    int row = blockIdx.x >> 3, c = blockIdx.x & 7;
    const float* p = fq + (size_t)row * N_GT + c * SCH;
    float s = 0.f;
    for (int i = threadIdx.x; i < SCH; i += 256) s += __expf(p[i]);
    s = block_sum(s, red);
    if (threadIdx.x == 0) rowsum[blockIdx.x] = s;
}

// ---------------- softmax pass 2: write bf16 fqm, skew, fitness pass-1 ----
// For pair t=row (row<49): this row is p0, row+1 is p1 (recomputed from fq +
// rowsum, L3-hot). Accumulates weight = sum(p1*mask), S5 = sum(p0*e^{5f}*mask)
// into pairW/pairS5 via per-block atomics (8 chunk-blocks per pair).
__global__ __launch_bounds__(256) void softmax_write_kernel(
    const float* __restrict__ fq, const float* __restrict__ rowsum,
    const float* __restrict__ fitv, unsigned short* __restrict__ fqmb,
    float* __restrict__ out, float* __restrict__ pairW,
    float* __restrict__ pairS5) {
    __shared__ float red[8];
    int row = blockIdx.x >> 3, c = blockIdx.x & 7;
    float S = 0.f;
#pragma unroll
    for (int j = 0; j < 8; ++j) S += rowsum[row * 8 + j];
    float inv = 1.f / S;
    bool hasPair = row < N_T - 1;
    float invn = 0.f;
    if (hasPair) {
        float Sn = 0.f;
#pragma unroll
        for (int j = 0; j < 8; ++j) Sn += rowsum[(row + 1) * 8 + j];
        invn = 1.f / Sn;
    }

    const float* p  = fq + (size_t)row * N_GT + c * SCH;
    const float* p1 = p + N_GT;
    const float* fv = fitv + c * SCH;
    unsigned short* yb = fqmb + (size_t)row * N_GT + c * SCH;
    const float mean = 1.f / (float)N_GT;
    float skew = 0.f, wsum = 0.f, s5 = 0.f;
    for (int i = threadIdx.x; i < SCH; i += 256) {
        float y = __expf(p[i]) * inv;
        unsigned ub = __float_as_uint(y);           // RTN f32 -> bf16
        yb[i] = (unsigned short)((ub + 0x7FFFu + ((ub >> 16) & 1u)) >> 16);
        float d = y - mean;
        skew += d * d * d;
        if (hasPair) {
            bool m = y >= 1e-6f;
            float y1 = __expf(p1[i]) * invn;
            float e5 = __expf(5.f * fv[i]);
            wsum += m ? y1 : 0.f;
            s5   += m ? y * e5 : 0.f;
        }
    }
    skew = block_sum(skew, red);
    if (threadIdx.x == 0)
        atomicAdd(out + 400001, skew * (-1.f / ((float)N_GT * (float)N_T)));
    if (hasPair) {
        wsum = block_sum(wsum, red);
        s5 = block_sum(s5, red);
        if (threadIdx.x == 0) {
            atomicAdd(&pairW[row], wsum);
            atomicAdd(&pairS5[row], s5);
        }
    }
}

// ---------------- fitness pass 2: KL using telescoped replicator ----------
// ips after 5 steps = p0*e^{5f}/S5; kl = sum np1*(log np1 - (log p0 + 5f - log S5))
__global__ __launch_bounds__(256) void fit2_kernel(
    const float* __restrict__ fq, const float* __restrict__ rowsum,
    const float* __restrict__ fitv, const float* __restrict__ pairW,
    const float* __restrict__ pairS5, float* __restrict__ out) {
    __shared__ float red[8];
    int t = blockIdx.x >> 3, c = blockIdx.x & 7;
    float weight = pairW[t];
    if (weight < 0.3f) return;                      // block-uniform
    float S = 0.f, Sn = 0.f;
#pragma unroll
    for (int j = 0; j < 8; ++j) {
        S  += rowsum[t * 8 + j];
        Sn += rowsum[(t + 1) * 8 + j];
    }
    float inv = 1.f / S, invn = 1.f / Sn;
    float invw = 1.f / weight;
    float lS5 = __logf(pairS5[t]);

    const float* q0 = fq + (size_t)t * N_GT + c * SCH;
    const float* q1 = q0 + N_GT;
    const float* fv = fitv + c * SCH;
    float kls = 0.f;
    for (int i = threadIdx.x; i < SCH; i += 256) {
        float y = __expf(q0[i]) * inv;
        if (y >= 1e-6f) {
            float y1 = __expf(q1[i]) * invn;
            float np1 = y1 * invw;
            kls += np1 * (__logf(np1) - (__logf(y) + 5.f * fv[i] - lS5));
        }
    }
    kls = block_sum(kls, red);
    if (threadIdx.x == 0)
        atomicAdd(out + 400000, weight * kls * (1.f / (float)(N_T - 1)));
}

// ---------------- MFMA GEMM, 3-buffer counted-vmcnt pipeline ----------------
// partial[s][t][p] = sum_{g in slice s} fqm[t][g] * B[g][p]
// B tile (32k x 256p fp32, 32 KB) rotates through 3 LDS buffers staged by
// global_load_lds dwordx4. Counted s_waitcnt vmcnt(8) + raw s_barrier keeps
// the next tile's 8 loads/wave in flight across the barrier (no vmcnt(0)
// drain). A fragments double-buffered in regs, loaded BEFORE the stage issue
// so the compiler's A-wait leaves the staging queue intact.
__global__ __launch_bounds__(256, 1) void gemm_mfma_kernel(
    const float* __restrict__ B, const unsigned short* __restrict__ Abf,
    float* __restrict__ partial, int ch) {
    __shared__ __align__(16) float lds[3][KTILE][PBLK];   // 96 KB -> 1 block/CU
    const int tid = threadIdx.x;
    const int l = tid & 63, w = tid >> 6;
    const int ln = l & 15, kq = l >> 4;
    const int kq8 = kq * 8;
    const int woff = w * 64;
    const int pblk = blockIdx.x * PBLK;
    const int s = blockIdx.y;

    const int ks0 = s * ch;
    int ks1 = ks0 + ch; if (ks1 > KSTEPS) ks1 = KSTEPS;
    const int nk = ks1 - ks0;
    if (nk <= 0) return;

    int scol = pblk + l * 4;
    if (scol > NPA - 4) scol = NPA - 4;   // last block: dup loads, stores guarded

    const unsigned short* abase = Abf + (size_t)ln * N_GT;

    f32x4 acc[4][4];
#pragma unroll
    for (int mt = 0; mt < 4; ++mt)
#pragma unroll
        for (int nt = 0; nt < 4; ++nt)
            acc[mt][nt] = (f32x4){0.f, 0.f, 0.f, 0.f};

    short8 avA[4], avB[4];

#define STAGE(BUF, KS) do {                                                    \
    const float* gsrc_ = B + (size_t)(KS) * (KTILE * NPA) + scol;              \
    _Pragma("unroll") for (int it_ = 0; it_ < 8; ++it_) {                      \
        int row_ = w * 8 + it_;                                                \
        __builtin_amdgcn_global_load_lds(                                      \
            (const __attribute__((address_space(1))) void*)(gsrc_ + (size_t)row_ * NPA), \
            (__attribute__((address_space(3))) void*)&lds[BUF][row_][0],       \
            16, 0, 0);                                                         \
    }                                                                          \
} while (0)

#define LOADA(AV, KS) do {                                                     \
    const int k0_ = (KS) * 32 + kq8;                                           \
    _Pragma("unroll") for (int mt_ = 0; mt_ < 4; ++mt_)                        \
        AV[mt_] = *(const short8*)(abase + (size_t)(mt_ * 16) * N_GT + k0_);   \
} while (0)

#define COMPUTE(BUF, AV) do {                                                  \
    f32x4 f_[8];                                                               \
    _Pragma("unroll") for (int j_ = 0; j_ < 8; ++j_)                           \
        f_[j_] = *(const f32x4*)&lds[BUF][kq8 + j_][woff + ln * 4];            \
    _Pragma("unroll") for (int nt_ = 0; nt_ < 4; ++nt_) {                      \
        short8 bb_;                                                            \
        _Pragma("unroll") for (int j_ = 0; j_ < 8; ++j_)                       \
            bb_[j_] = (short)(__float_as_uint(f_[j_][nt_]) >> 16);             \
        _Pragma("unroll") for (int mt_ = 0; mt_ < 4; ++mt_)                    \
            acc[mt_][nt_] = __builtin_amdgcn_mfma_f32_16x16x32_bf16(           \
                AV[mt_], bb_, acc[mt_][nt_], 0, 0, 0);                         \
    }                                                                          \
} while (0)

    STAGE(0, ks0);
    if (nk > 1) STAGE(1, ks0 + 1);
    LOADA(avA, ks0);

    int cur = 0;
#pragma unroll 1
    for (int i = 0; i < nk; ++i) {
        // tile i's 8 stage-loads/wave are the oldest; exactly 8 newer (tile
        // i+1's stage) remain in flight -> vmcnt(8). Last iter: drain.
        if (i < nk - 1) asm volatile("s_waitcnt vmcnt(8)" ::: "memory");
        else            asm volatile("s_waitcnt vmcnt(0)" ::: "memory");
        __builtin_amdgcn_s_barrier();
        asm volatile("" ::: "memory");             // no LDS reads above barrier
        if (i + 1 < nk) {
            if (i & 1) LOADA(avA, ks0 + i + 1); else LOADA(avB, ks0 + i + 1);
        }
        if (i + 2 < nk) {
            int nb = cur + 2; if (nb >= 3) nb -= 3;
            STAGE(nb, ks0 + i + 2);
        }
        if (i & 1) COMPUTE(cur, avB); else COMPUTE(cur, avA);
        ++cur; if (cur == 3) cur = 0;
    }

#undef STAGE
#undef LOADA
#undef COMPUTE

    const int rbase = kq * 4;
    const int pst = pblk + woff + ln * 4;
    float* ps = partial + (size_t)s * (N_T * NPA);
    if (pst < NPA) {
#pragma unroll
        for (int mt = 0; mt < 4; ++mt) {
#pragma unroll
            for (int r = 0; r < 4; ++r) {
                int t = mt * 16 + rbase + r;
                if (t < N_T) {
                    float4 v = {acc[mt][0][r], acc[mt][1][r],
                                acc[mt][2][r], acc[mt][3][r]};
                    *reinterpret_cast<float4*>(ps + (size_t)t * NPA + pst) = v;
                }
            }
        }
    }
}

// ---------------- reduce partials + log (float4) ----------------
__global__ __launch_bounds__(256) void reduce_log_kernel(
    const float4* __restrict__ partial, float4* __restrict__ out, int ns) {
    int i = blockIdx.x * 256 + threadIdx.x;
    if (i >= (N_T * NPA) / 4) return;
    float4 s = {0.f, 0.f, 0.f, 0.f};
    for (int k = 0; k < ns; ++k) {
        float4 v = partial[(size_t)k * ((N_T * NPA) / 4) + i];
        s.x += v.x; s.y += v.y; s.z += v.z; s.w += v.w;
    }
    const float r = 1.f / (float)N_POS;
    float4 o;
    o.x = __logf(s.x * r + 1e-10f);
    o.y = __logf(s.y * r + 1e-10f);
    o.z = __logf(s.z * r + 1e-10f);
    o.w = __logf(s.w * r + 1e-10f);
    out[i] = o;
}

extern "C" void kernel_launch(void* const* d_in, const int* in_sizes, int n_in,
                              void* d_out, int out_size, void* d_ws, size_t ws_size,
                              hipStream_t stream) {
    const float* fitness = (const float*)d_in[0];
    const float* fq_mat  = (const float*)d_in[1];
    const float* geno    = (const float*)d_in[2];
    float* out = (float*)d_out;

    char* ws = (char*)d_ws;
    unsigned short* fqmb = (unsigned short*)ws;          // 64*20000*2 = 2,560,000 B
    float* rowsum        = (float*)(ws + 2560000);       // 400*4 = 1,600 B
    float* pairW         = (float*)(ws + 2561600);       // 49*4
    float* pairS5        = (float*)(ws + 2561856);       // 49*4
    float* partial       = (float*)(ws + 2564096);       // NS*50*8000*4 = 12.8 MB

    const int ch = (KSTEPS + NS - 1) / NS;               // 79

    // zero scalar-loss outputs, pair accumulators, bf16 A-pad rows 50..63
    hipMemsetAsync((char*)d_out + (size_t)400000 * sizeof(float), 0, 2 * sizeof(float), stream);
    hipMemsetAsync(ws + 2561600, 0, 512, stream);
    hipMemsetAsync((char*)fqmb + (size_t)N_T * N_GT * sizeof(unsigned short), 0,
                   (size_t)14 * N_GT * sizeof(unsigned short), stream);

    hipLaunchKernelGGL(softmax_sum_kernel, dim3(N_T * 8), dim3(256), 0, stream,
                       fq_mat, rowsum);
    hipLaunchKernelGGL(softmax_write_kernel, dim3(N_T * 8), dim3(256), 0, stream,
                       fq_mat, rowsum, fitness, fqmb, out, pairW, pairS5);
    hipLaunchKernelGGL(fit2_kernel, dim3((N_T - 1) * 8), dim3(256), 0, stream,
                       fq_mat, rowsum, fitness, pairW, pairS5, out);
    hipLaunchKernelGGL(gemm_mfma_kernel, dim3((NPA + PBLK - 1) / PBLK, NS), dim3(256), 0, stream,
                       geno, fqmb, partial, ch);
    hipLaunchKernelGGL(reduce_log_kernel, dim3(((N_T * NPA) / 4 + 255) / 256), dim3(256), 0, stream,
                       (const float4*)partial, (float4*)out, NS);
}

// Round 7
// 160.484 us; speedup vs baseline: 1.2612x; 1.2612x over previous
//
#include <hip/hip_runtime.h>
#include <cfloat>
#include <cstdint>

#define N_GT 20000
#define N_T 50
#define NPA 8000          // N_POS * ALPHA
#define N_POS 2000
#define KSTEPS 625        // N_GT / 32
#define KTILE 32          // k rows per LDS tile
#define PBLK 256          // p columns per block
#define NS 16             // split-K slices (32 x 16 = 512 blocks = 2/CU)
#define SCH 2500          // softmax chunk (8 chunks per row)

typedef __attribute__((ext_vector_type(8))) short short8;
typedef __attribute__((ext_vector_type(4))) float f32x4;

// ---------------- block reduction helpers ----------------
__device__ __forceinline__ float wave_sum(float v) {
#pragma unroll
    for (int o = 32; o > 0; o >>= 1) v += __shfl_down(v, o, 64);
    return v;
}
__device__ float block_sum(float v, float* red) {
    int lane = threadIdx.x & 63, wid = threadIdx.x >> 6, nw = blockDim.x >> 6;
    v = wave_sum(v);
    __syncthreads();
    if (lane == 0) red[wid] = v;
    __syncthreads();
    if (wid == 0) {
        float x = (lane < nw) ? red[lane] : 0.f;
        x = wave_sum(x);
        if (lane == 0) red[0] = x;
    }
    __syncthreads();
    return red[0];
}

// ---------------- softmax pass 1: per-chunk sum of exp ----------------
__global__ __launch_bounds__(256) void softmax_sum_kernel(
    const float* __restrict__ fq, float* __restrict__ rowsum) {
    __shared__ float red[8];
    int row = blockIdx.x >> 3, c = blockIdx.x & 7;
    const float* p = fq + (size_t)row * N_GT + c * SCH;
    float s = 0.f;
    for (int i = threadIdx.x; i < SCH; i += 256) s += __expf(p[i]);
    s = block_sum(s, red);
    if (threadIdx.x == 0) rowsum[blockIdx.x] = s;
}

// ---------------- softmax pass 2: bf16 fqm, skew, fused fitness stats ----
// Per pair t=row (row<49): accumulates W = sum(p1*mask), S5 = sum(p0*e^{5f}*mask),
// KLraw = sum_masked y1*(log y1 - log y0 - 5f)  [logs computed as q - logS: free].
// Final loss_t = KLraw + W*(log S5 - log W), assembled in finalize_kernel.
__global__ __launch_bounds__(256) void softmax_write_kernel(
    const float* __restrict__ fq, const float* __restrict__ rowsum,
    const float* __restrict__ fitv, unsigned short* __restrict__ fqmb,
    float* __restrict__ out, float* __restrict__ pairW,
    float* __restrict__ pairS5, float* __restrict__ pairKL) {
    __shared__ float red[8];
    int row = blockIdx.x >> 3, c = blockIdx.x & 7;
    float S = 0.f;
#pragma unroll
    for (int j = 0; j < 8; ++j) S += rowsum[row * 8 + j];
    float inv = 1.f / S, lS = __logf(S);
    bool hasPair = row < N_T - 1;
    float invn = 0.f, lSn = 0.f;
    if (hasPair) {
        float Sn = 0.f;
#pragma unroll
        for (int j = 0; j < 8; ++j) Sn += rowsum[(row + 1) * 8 + j];
        invn = 1.f / Sn; lSn = __logf(Sn);
    }

    const float* p  = fq + (size_t)row * N_GT + c * SCH;
    const float* p1 = p + N_GT;
    const float* fv = fitv + c * SCH;
    unsigned short* yb = fqmb + (size_t)row * N_GT + c * SCH;
    const float mean = 1.f / (float)N_GT;
    float skew = 0.f, wsum = 0.f, s5 = 0.f, kraw = 0.f;
    for (int i = threadIdx.x; i < SCH; i += 256) {
        float q0 = p[i];
        float y = __expf(q0) * inv;
        unsigned ub = __float_as_uint(y);           // RTN f32 -> bf16
        yb[i] = (unsigned short)((ub + 0x7FFFu + ((ub >> 16) & 1u)) >> 16);
        float d = y - mean;
        skew += d * d * d;
        if (hasPair) {
            float q1 = p1[i];
            float y1 = __expf(q1) * invn;
            float f5 = 5.f * fv[i];
            bool m = y >= 1e-6f;
            float y1m = m ? y1 : 0.f;
            wsum += y1m;
            s5   += m ? y * __expf(f5) : 0.f;
            kraw += y1m * (q1 - lSn - q0 + lS - f5);
        }
    }
    skew = block_sum(skew, red);
    if (threadIdx.x == 0)
        atomicAdd(out + 400001, skew * (-1.f / ((float)N_GT * (float)N_T)));
    if (hasPair) {
        wsum = block_sum(wsum, red);
        s5 = block_sum(s5, red);
        kraw = block_sum(kraw, red);
        if (threadIdx.x == 0) {
            atomicAdd(&pairW[row], wsum);
            atomicAdd(&pairS5[row], s5);
            atomicAdd(&pairKL[row], kraw);
        }
    }
}

// ---------------- finalize: assemble fitness loss (1 block, 64 threads) ----
__global__ __launch_bounds__(64) void finalize_kernel(
    const float* __restrict__ pairW, const float* __restrict__ pairS5,
    const float* __restrict__ pairKL, float* __restrict__ out) {
    int t = threadIdx.x;
    float v = 0.f;
    if (t < N_T - 1) {
        float W = pairW[t];
        if (W >= 0.3f)
            v = pairKL[t] + W * (__logf(pairS5[t]) - __logf(W));
    }
    v = wave_sum(v);
    if (t == 0) out[400000] = v * (1.f / (float)(N_T - 1));
}

// ---------------- MFMA GEMM with global_load_lds-staged B (round-5 struct) ----
// partial[s][t][p] = sum_{g in slice s} fqm[t][g] * B[g][p]
// B tile (32k x 256p fp32, 32KB) double-buffered in LDS via async
// global_load_lds dwordx4; 2 blocks/CU (64KB) -> 8 waves/CU of implicit
// overlap. (Round 6 lesson: 96KB 3-buffer counted-vmcnt at 1 block/CU
// REGRESSED 30% -- wave TLP beats explicit pipelining here.)
__global__ __launch_bounds__(256, 2) void gemm_mfma_kernel(
    const float* __restrict__ B, const unsigned short* __restrict__ Abf,
    float* __restrict__ partial, int ch) {
    __shared__ __align__(16) float lds[2][KTILE][PBLK];   // 64 KB
    const int tid = threadIdx.x;
    const int l = tid & 63, w = tid >> 6;
    const int ln = l & 15, kq = l >> 4;
    const int kq8 = kq * 8;
    const int woff = w * 64;
    const int pblk = blockIdx.x * PBLK;
    const int s = blockIdx.y;

    const int ks0 = s * ch;
    int ks1 = ks0 + ch; if (ks1 > KSTEPS) ks1 = KSTEPS;
    const int nk = ks1 - ks0;
    if (nk <= 0) return;

    int scol = pblk + l * 4;
    if (scol > NPA - 4) scol = NPA - 4;   // last block: dup loads, stores guarded

    const unsigned short* abase = Abf + (size_t)ln * N_GT;

    f32x4 acc[4][4];
#pragma unroll
    for (int mt = 0; mt < 4; ++mt)
#pragma unroll
        for (int nt = 0; nt < 4; ++nt)
            acc[mt][nt] = (f32x4){0.f, 0.f, 0.f, 0.f};

    short8 a0[4], a1[4];

#define STAGE(BUF, KS) do {                                                    \
    const float* gsrc_ = B + (size_t)(KS) * (KTILE * NPA) + scol;              \
    _Pragma("unroll") for (int it_ = 0; it_ < 8; ++it_) {                      \
        int row_ = w * 8 + it_;                                                \
        __builtin_amdgcn_global_load_lds(                                      \
            (const __attribute__((address_space(1))) void*)(gsrc_ + (size_t)row_ * NPA), \
            (__attribute__((address_space(3))) void*)&lds[BUF][row_][0],       \
            16, 0, 0);                                                         \
    }                                                                          \
} while (0)

#define LOADA(AV, KS) do {                                                     \
    const int k0_ = (KS) * 32 + kq8;                                           \
    _Pragma("unroll") for (int mt_ = 0; mt_ < 4; ++mt_)                        \
        AV[mt_] = *(const short8*)(abase + (size_t)(mt_ * 16) * N_GT + k0_);   \
} while (0)

#define COMPUTE(BUF, AV) do {                                                  \
    f32x4 f_[8];                                                               \
    _Pragma("unroll") for (int j_ = 0; j_ < 8; ++j_)                           \
        f_[j_] = *(const f32x4*)&lds[BUF][kq8 + j_][woff + ln * 4];            \
    _Pragma("unroll") for (int nt_ = 0; nt_ < 4; ++nt_) {                      \
        short8 bb_;                                                            \
        _Pragma("unroll") for (int j_ = 0; j_ < 8; ++j_)                       \
            bb_[j_] = (short)(__float_as_uint(f_[j_][nt_]) >> 16);             \
        _Pragma("unroll") for (int mt_ = 0; mt_ < 4; ++mt_)                    \
            acc[mt_][nt_] = __builtin_amdgcn_mfma_f32_16x16x32_bf16(           \
                AV[mt_], bb_, acc[mt_][nt_], 0, 0, 0);                         \
    }                                                                          \
} while (0)

    STAGE(0, ks0);
    LOADA(a0, ks0);
    int i = 0;
    for (; i + 1 < nk; i += 2) {
        __syncthreads();                       // tile i staged & prev reads done
        STAGE(1, ks0 + i + 1);
        LOADA(a1, ks0 + i + 1);
        COMPUTE(0, a0);
        __syncthreads();                       // tile i+1 staged & reads of buf0 done
        if (i + 2 < nk) { STAGE(0, ks0 + i + 2); LOADA(a0, ks0 + i + 2); }
        COMPUTE(1, a1);
    }
    if (i < nk) {                              // odd tail (tile in buf 0)
        __syncthreads();
        COMPUTE(0, a0);
    }

#undef STAGE
#undef LOADA
#undef COMPUTE

    const int rbase = kq * 4;
    const int pst = pblk + woff + ln * 4;
    float* ps = partial + (size_t)s * (N_T * NPA);
    if (pst < NPA) {
#pragma unroll
        for (int mt = 0; mt < 4; ++mt) {
#pragma unroll
            for (int r = 0; r < 4; ++r) {
                int t = mt * 16 + rbase + r;
                if (t < N_T) {
                    float4 v = {acc[mt][0][r], acc[mt][1][r],
                                acc[mt][2][r], acc[mt][3][r]};
                    *reinterpret_cast<float4*>(ps + (size_t)t * NPA + pst) = v;
                }
            }
        }
    }
}

// ---------------- reduce partials + log (float4) ----------------
__global__ __launch_bounds__(256) void reduce_log_kernel(
    const float4* __restrict__ partial, float4* __restrict__ out, int ns) {
    int i = blockIdx.x * 256 + threadIdx.x;
    if (i >= (N_T * NPA) / 4) return;
    float4 s = {0.f, 0.f, 0.f, 0.f};
    for (int k = 0; k < ns; ++k) {
        float4 v = partial[(size_t)k * ((N_T * NPA) / 4) + i];
        s.x += v.x; s.y += v.y; s.z += v.z; s.w += v.w;
    }
    const float r = 1.f / (float)N_POS;
    float4 o;
    o.x = __logf(s.x * r + 1e-10f);
    o.y = __logf(s.y * r + 1e-10f);
    o.z = __logf(s.z * r + 1e-10f);
    o.w = __logf(s.w * r + 1e-10f);
    out[i] = o;
}

extern "C" void kernel_launch(void* const* d_in, const int* in_sizes, int n_in,
                              void* d_out, int out_size, void* d_ws, size_t ws_size,
                              hipStream_t stream) {
    const float* fitness = (const float*)d_in[0];
    const float* fq_mat  = (const float*)d_in[1];
    const float* geno    = (const float*)d_in[2];
    float* out = (float*)d_out;

    char* ws = (char*)d_ws;
    unsigned short* fqmb = (unsigned short*)ws;          // 64*20000*2 = 2,560,000 B
    float* rowsum        = (float*)(ws + 2560000);       // 400*4 = 1,600 B
    float* pairW         = (float*)(ws + 2561600);       // 49*4
    float* pairS5        = (float*)(ws + 2561856);       // 49*4
    float* pairKL        = (float*)(ws + 2562112);       // 49*4
    float* partial       = (float*)(ws + 2564096);       // NS*50*8000*4 = 25.6 MB

    const int ch = (KSTEPS + NS - 1) / NS;               // 40

    // zero scalar-loss outputs, pair accumulators, bf16 A-pad rows 50..63
    hipMemsetAsync((char*)d_out + (size_t)400000 * sizeof(float), 0, 2 * sizeof(float), stream);
    hipMemsetAsync(ws + 2561600, 0, 1024, stream);
    hipMemsetAsync((char*)fqmb + (size_t)N_T * N_GT * sizeof(unsigned short), 0,
                   (size_t)14 * N_GT * sizeof(unsigned short), stream);

    hipLaunchKernelGGL(softmax_sum_kernel, dim3(N_T * 8), dim3(256), 0, stream,
                       fq_mat, rowsum);
    hipLaunchKernelGGL(softmax_write_kernel, dim3(N_T * 8), dim3(256), 0, stream,
                       fq_mat, rowsum, fitness, fqmb, out, pairW, pairS5, pairKL);
    hipLaunchKernelGGL(finalize_kernel, dim3(1), dim3(64), 0, stream,
                       pairW, pairS5, pairKL, out);
    hipLaunchKernelGGL(gemm_mfma_kernel, dim3((NPA + PBLK - 1) / PBLK, NS), dim3(256), 0, stream,
                       geno, fqmb, partial, ch);
    hipLaunchKernelGGL(reduce_log_kernel, dim3(((N_T * NPA) / 4 + 255) / 256), dim3(256), 0, stream,
                       (const float4*)partial, (float4*)out, NS);
}

// Round 8
// 148.910 us; speedup vs baseline: 1.3593x; 1.0777x over previous
//
#include <hip/hip_runtime.h>
#include <cfloat>
#include <cstdint>

#define N_GT 20000
#define N_T 50
#define NPA 8000          // N_POS * ALPHA
#define N_POS 2000
#define KSTEPS 625        // N_GT / 32
#define KTILE 32          // k rows per LDS tile
#define PBLK 256          // p columns per block
#define NS 16             // split-K slices (32 x 16 = 512 blocks = 2/CU)
#define SCH 2500          // softmax chunk (8 chunks per row)

typedef __attribute__((ext_vector_type(8))) short short8;
typedef __attribute__((ext_vector_type(4))) float f32x4;

// ---------------- block reduction helpers ----------------
__device__ __forceinline__ float wave_sum(float v) {
#pragma unroll
    for (int o = 32; o > 0; o >>= 1) v += __shfl_down(v, o, 64);
    return v;
}
__device__ float block_sum(float v, float* red) {
    int lane = threadIdx.x & 63, wid = threadIdx.x >> 6, nw = blockDim.x >> 6;
    v = wave_sum(v);
    __syncthreads();
    if (lane == 0) red[wid] = v;
    __syncthreads();
    if (wid == 0) {
        float x = (lane < nw) ? red[lane] : 0.f;
        x = wave_sum(x);
        if (lane == 0) red[0] = x;
    }
    __syncthreads();
    return red[0];
}

// ---------------- softmax pass 1: per-chunk sum of exp ----------------
__global__ __launch_bounds__(256) void softmax_sum_kernel(
    const float* __restrict__ fq, float* __restrict__ rowsum) {
    __shared__ float red[8];
    int row = blockIdx.x >> 3, c = blockIdx.x & 7;
    const float* p = fq + (size_t)row * N_GT + c * SCH;
    float s = 0.f;
    for (int i = threadIdx.x; i < SCH; i += 256) s += __expf(p[i]);
    s = block_sum(s, red);
    if (threadIdx.x == 0) rowsum[blockIdx.x] = s;
}

// ---------------- softmax pass 2: bf16 fqm, skew + fitness stats (slots) ----
// Grid 64x8: rows 50..63 only zero the fqmb pad chunk (no memset dispatch).
// Rows <50: write bf16 fqm, per-block skew slot; rows <49 also accumulate
// W = sum(p1*mask), S5 = sum(p0*e^{5f}*mask),
// KLraw = sum_masked y1*(log y1 - log y0 - 5f)  [logs as q - logS: free]
// into per-block slots (plain stores, no atomics, no zeroing needed).
__global__ __launch_bounds__(256) void softmax_write_kernel(
    const float* __restrict__ fq, const float* __restrict__ rowsum,
    const float* __restrict__ fitv, unsigned short* __restrict__ fqmb,
    float* __restrict__ skewS, float* __restrict__ pairW,
    float* __restrict__ pairS5, float* __restrict__ pairKL) {
    __shared__ float red[8];
    int row = blockIdx.x >> 3, c = blockIdx.x & 7;
    unsigned short* yb = fqmb + (size_t)row * N_GT + c * SCH;

    if (row >= N_T) {                    // pad rows 50..63: zero, done
        uint2* z = reinterpret_cast<uint2*>(yb);
        for (int i = threadIdx.x; i < SCH / 4; i += 256) z[i] = (uint2){0u, 0u};
        return;
    }

    float S = 0.f;
#pragma unroll
    for (int j = 0; j < 8; ++j) S += rowsum[row * 8 + j];
    float inv = 1.f / S, lS = __logf(S);
    bool hasPair = row < N_T - 1;
    float invn = 0.f, lSn = 0.f;
    if (hasPair) {
        float Sn = 0.f;
#pragma unroll
        for (int j = 0; j < 8; ++j) Sn += rowsum[(row + 1) * 8 + j];
        invn = 1.f / Sn; lSn = __logf(Sn);
    }

    const float* p  = fq + (size_t)row * N_GT + c * SCH;
    const float* p1 = p + N_GT;
    const float* fv = fitv + c * SCH;
    const float mean = 1.f / (float)N_GT;
    float skew = 0.f, wsum = 0.f, s5 = 0.f, kraw = 0.f;
    for (int i = threadIdx.x; i < SCH; i += 256) {
        float q0 = p[i];
        float y = __expf(q0) * inv;
        unsigned ub = __float_as_uint(y);           // RTN f32 -> bf16
        yb[i] = (unsigned short)((ub + 0x7FFFu + ((ub >> 16) & 1u)) >> 16);
        float d = y - mean;
        skew += d * d * d;
        if (hasPair) {
            float q1 = p1[i];
            float y1 = __expf(q1) * invn;
            float f5 = 5.f * fv[i];
            bool m = y >= 1e-6f;
            float y1m = m ? y1 : 0.f;
            wsum += y1m;
            s5   += m ? y * __expf(f5) : 0.f;
            kraw += y1m * (q1 - lSn - q0 + lS - f5);
        }
    }
    skew = block_sum(skew, red);
    if (threadIdx.x == 0) skewS[blockIdx.x] = skew;
    if (hasPair) {
        wsum = block_sum(wsum, red);
        s5 = block_sum(s5, red);
        kraw = block_sum(kraw, red);
        if (threadIdx.x == 0) {
            pairW[c * 64 + row] = wsum;
            pairS5[c * 64 + row] = s5;
            pairKL[c * 64 + row] = kraw;
        }
    }
}

// ---------------- finalize: both scalar losses (1 block, 512 threads) ----
__global__ __launch_bounds__(512) void finalize_kernel(
    const float* __restrict__ skewS, const float* __restrict__ pairW,
    const float* __restrict__ pairS5, const float* __restrict__ pairKL,
    float* __restrict__ out) {
    __shared__ float red[8];
    float sk = 0.f;
    for (int i = threadIdx.x; i < N_T * 8; i += 512) sk += skewS[i];
    sk = block_sum(sk, red);
    if (threadIdx.x == 0)
        out[400001] = sk * (-1.f / ((float)N_GT * (float)N_T));

    if (threadIdx.x < 64) {             // wave 0 handles the 49 pairs
        int t = threadIdx.x;
        float v = 0.f;
        if (t < N_T - 1) {
            float W = 0.f, S5 = 0.f, KL = 0.f;
#pragma unroll
            for (int c = 0; c < 8; ++c) {
                W  += pairW[c * 64 + t];
                S5 += pairS5[c * 64 + t];
                KL += pairKL[c * 64 + t];
            }
            if (W >= 0.3f)
                v = KL + W * (__logf(S5) - __logf(W));
        }
        v = wave_sum(v);
        if (t == 0) out[400000] = v * (1.f / (float)(N_T - 1));
    }
}

// ---------------- MFMA GEMM with global_load_lds-staged B ----------------
// partial[s][t][p] = sum_{g in slice s} fqm[t][g] * B[g][p]
// B tile (32k x 256p fp32, 32KB) double-buffered in LDS via async
// global_load_lds dwordx4; 2 blocks/CU (64KB) -> 8 waves/CU of implicit
// overlap. (Round 6 lesson: 96KB 3-buffer counted-vmcnt at 1 block/CU
// REGRESSED 30% -- wave TLP beats explicit pipelining here.)
// Balanced split-K: slice s covers [(s*625)/16, ((s+1)*625)/16) -> 39/40.
__global__ __launch_bounds__(256, 2) void gemm_mfma_kernel(
    const float* __restrict__ B, const unsigned short* __restrict__ Abf,
    float* __restrict__ partial) {
    __shared__ __align__(16) float lds[2][KTILE][PBLK];   // 64 KB
    const int tid = threadIdx.x;
    const int l = tid & 63, w = tid >> 6;
    const int ln = l & 15, kq = l >> 4;
    const int kq8 = kq * 8;
    const int woff = w * 64;
    const int pblk = blockIdx.x * PBLK;
    const int s = blockIdx.y;

    const int ks0 = (s * KSTEPS) / NS;
    const int ks1 = ((s + 1) * KSTEPS) / NS;
    const int nk = ks1 - ks0;

    int scol = pblk + l * 4;
    if (scol > NPA - 4) scol = NPA - 4;   // last block: dup loads, stores guarded

    const unsigned short* abase = Abf + (size_t)ln * N_GT;

    f32x4 acc[4][4];
#pragma unroll
    for (int mt = 0; mt < 4; ++mt)
#pragma unroll
        for (int nt = 0; nt < 4; ++nt)
            acc[mt][nt] = (f32x4){0.f, 0.f, 0.f, 0.f};

    short8 a0[4], a1[4];

#define STAGE(BUF, KS) do {                                                    \
    const float* gsrc_ = B + (size_t)(KS) * (KTILE * NPA) + scol;              \
    _Pragma("unroll") for (int it_ = 0; it_ < 8; ++it_) {                      \
        int row_ = w * 8 + it_;                                                \
        __builtin_amdgcn_global_load_lds(                                      \
            (const __attribute__((address_space(1))) void*)(gsrc_ + (size_t)row_ * NPA), \
            (__attribute__((address_space(3))) void*)&lds[BUF][row_][0],       \
            16, 0, 0);                                                         \
    }                                                                          \
} while (0)

#define LOADA(AV, KS) do {                                                     \
    const int k0_ = (KS) * 32 + kq8;                                           \
    _Pragma("unroll") for (int mt_ = 0; mt_ < 4; ++mt_)                        \
        AV[mt_] = *(const short8*)(abase + (size_t)(mt_ * 16) * N_GT + k0_);   \
} while (0)

#define COMPUTE(BUF, AV) do {                                                  \
    f32x4 f_[8];                                                               \
    _Pragma("unroll") for (int j_ = 0; j_ < 8; ++j_)                           \
        f_[j_] = *(const f32x4*)&lds[BUF][kq8 + j_][woff + ln * 4];            \
    _Pragma("unroll") for (int nt_ = 0; nt_ < 4; ++nt_) {                      \
        short8 bb_;                                                            \
        _Pragma("unroll") for (int j_ = 0; j_ < 8; ++j_)                       \
            bb_[j_] = (short)(__float_as_uint(f_[j_][nt_]) >> 16);             \
        _Pragma("unroll") for (int mt_ = 0; mt_ < 4; ++mt_)                    \
            acc[mt_][nt_] = __builtin_amdgcn_mfma_f32_16x16x32_bf16(           \
                AV[mt_], bb_, acc[mt_][nt_], 0, 0, 0);                         \
    }                                                                          \
} while (0)

    STAGE(0, ks0);
    LOADA(a0, ks0);
    int i = 0;
    for (; i + 1 < nk; i += 2) {
        __syncthreads();                       // tile i staged & prev reads done
        STAGE(1, ks0 + i + 1);
        LOADA(a1, ks0 + i + 1);
        COMPUTE(0, a0);
        __syncthreads();                       // tile i+1 staged & reads of buf0 done
        if (i + 2 < nk) { STAGE(0, ks0 + i + 2); LOADA(a0, ks0 + i + 2); }
        COMPUTE(1, a1);
    }
    if (i < nk) {                              // odd tail (tile in buf 0)
        __syncthreads();
        COMPUTE(0, a0);
    }

#undef STAGE
#undef LOADA
#undef COMPUTE

    const int rbase = kq * 4;
    const int pst = pblk + woff + ln * 4;
    float* ps = partial + (size_t)s * (N_T * NPA);
    if (pst < NPA) {
#pragma unroll
        for (int mt = 0; mt < 4; ++mt) {
#pragma unroll
            for (int r = 0; r < 4; ++r) {
                int t = mt * 16 + rbase + r;
                if (t < N_T) {
                    float4 v = {acc[mt][0][r], acc[mt][1][r],
                                acc[mt][2][r], acc[mt][3][r]};
                    *reinterpret_cast<float4*>(ps + (size_t)t * NPA + pst) = v;
                }
            }
        }
    }
}

// ---------------- reduce partials + log (float4) ----------------
__global__ __launch_bounds__(256) void reduce_log_kernel(
    const float4* __restrict__ partial, float4* __restrict__ out) {
    int i = blockIdx.x * 256 + threadIdx.x;
    if (i >= (N_T * NPA) / 4) return;
    float4 s = {0.f, 0.f, 0.f, 0.f};
    for (int k = 0; k < NS; ++k) {
        float4 v = partial[(size_t)k * ((N_T * NPA) / 4) + i];
        s.x += v.x; s.y += v.y; s.z += v.z; s.w += v.w;
    }
    const float r = 1.f / (float)N_POS;
    float4 o;
    o.x = __logf(s.x * r + 1e-10f);
    o.y = __logf(s.y * r + 1e-10f);
    o.z = __logf(s.z * r + 1e-10f);
    o.w = __logf(s.w * r + 1e-10f);
    out[i] = o;
}

extern "C" void kernel_launch(void* const* d_in, const int* in_sizes, int n_in,
                              void* d_out, int out_size, void* d_ws, size_t ws_size,
                              hipStream_t stream) {
    const float* fitness = (const float*)d_in[0];
    const float* fq_mat  = (const float*)d_in[1];
    const float* geno    = (const float*)d_in[2];
    float* out = (float*)d_out;

    char* ws = (char*)d_ws;
    unsigned short* fqmb = (unsigned short*)ws;          // 64*20000*2 = 2,560,000 B
    float* rowsum        = (float*)(ws + 2560000);       // 400*4 = 1,600 B
    float* skewS         = (float*)(ws + 2561600);       // 512*4 = 2,048 B
    float* pairW         = (float*)(ws + 2563648);       // 8*64*4 = 2,048 B
    float* pairS5        = (float*)(ws + 2565696);       // 2,048 B
    float* pairKL        = (float*)(ws + 2567744);       // 2,048 B
    float* partial       = (float*)(ws + 2570240);       // NS*50*8000*4 = 25.6 MB

    // no memsets: every buffer consumed is deterministically written first
    hipLaunchKernelGGL(softmax_sum_kernel, dim3(N_T * 8), dim3(256), 0, stream,
                       fq_mat, rowsum);
    hipLaunchKernelGGL(softmax_write_kernel, dim3(64 * 8), dim3(256), 0, stream,
                       fq_mat, rowsum, fitness, fqmb, skewS, pairW, pairS5, pairKL);
    hipLaunchKernelGGL(finalize_kernel, dim3(1), dim3(512), 0, stream,
                       skewS, pairW, pairS5, pairKL, out);
    hipLaunchKernelGGL(gemm_mfma_kernel, dim3(NPA / PBLK + 1, NS), dim3(256), 0, stream,
                       geno, fqmb, partial);
    hipLaunchKernelGGL(reduce_log_kernel, dim3(((N_T * NPA) / 4 + 255) / 256), dim3(256), 0, stream,
                       (const float4*)partial, (float4*)out);
}

// Round 9
// 139.321 us; speedup vs baseline: 1.4528x; 1.0688x over previous
//
#include <hip/hip_runtime.h>
#include <cfloat>
#include <cstdint>

#define N_GT 20000
#define N_T 50
#define NPA 8000          // N_POS * ALPHA
#define N_POS 2000
#define KSTEPS 625        // N_GT / 32
#define KTILE 32          // k rows per LDS tile
#define PBLK 256          // p columns per block
#define NS 16             // split-K slices (32 x 16 = 512 blocks = 2/CU)
#define SCH 2500          // softmax chunk (8 chunks per row)
#define NRED 391          // reduce blocks: ceil(100000/256)

typedef __attribute__((ext_vector_type(8))) short short8;
typedef __attribute__((ext_vector_type(4))) float f32x4;
typedef __attribute__((ext_vector_type(4))) unsigned short u16x4;

// ---------------- block reduction helpers ----------------
__device__ __forceinline__ float wave_sum(float v) {
#pragma unroll
    for (int o = 32; o > 0; o >>= 1) v += __shfl_down(v, o, 64);
    return v;
}
__device__ float block_sum(float v, float* red) {
    int lane = threadIdx.x & 63, wid = threadIdx.x >> 6, nw = blockDim.x >> 6;
    v = wave_sum(v);
    __syncthreads();
    if (lane == 0) red[wid] = v;
    __syncthreads();
    if (wid == 0) {
        float x = (lane < nw) ? red[lane] : 0.f;
        x = wave_sum(x);
        if (lane == 0) red[0] = x;
    }
    __syncthreads();
    return red[0];
}
__device__ __forceinline__ unsigned short f2bf_rtn(float x) {
    unsigned u = __float_as_uint(x);
    return (unsigned short)((u + 0x7FFFu + ((u >> 16) & 1u)) >> 16);
}

// ---------------- softmax pass 1: per-chunk sum of exp ----------------
__global__ __launch_bounds__(256) void softmax_sum_kernel(
    const float* __restrict__ fq, float* __restrict__ rowsum) {
    __shared__ float red[8];
    int row = blockIdx.x >> 3, c = blockIdx.x & 7;
    const float* p = fq + (size_t)row * N_GT + c * SCH;
    float s = 0.f;
    for (int i = threadIdx.x; i < SCH; i += 256) s += __expf(p[i]);
    s = block_sum(s, red);
    if (threadIdx.x == 0) rowsum[blockIdx.x] = s;
}

// ---------------- softmax pass 2: bf16 fqm, skew + fitness stats (slots) ----
__global__ __launch_bounds__(256) void softmax_write_kernel(
    const float* __restrict__ fq, const float* __restrict__ rowsum,
    const float* __restrict__ fitv, unsigned short* __restrict__ fqmb,
    float* __restrict__ skewS, float* __restrict__ pairW,
    float* __restrict__ pairS5, float* __restrict__ pairKL) {
    __shared__ float red[8];
    int row = blockIdx.x >> 3, c = blockIdx.x & 7;
    unsigned short* yb = fqmb + (size_t)row * N_GT + c * SCH;

    if (row >= N_T) {                    // pad rows 50..63: zero, done
        uint2* z = reinterpret_cast<uint2*>(yb);
        for (int i = threadIdx.x; i < SCH / 4; i += 256) z[i] = (uint2){0u, 0u};
        return;
    }

    float S = 0.f;
#pragma unroll
    for (int j = 0; j < 8; ++j) S += rowsum[row * 8 + j];
    float inv = 1.f / S, lS = __logf(S);
    bool hasPair = row < N_T - 1;
    float invn = 0.f, lSn = 0.f;
    if (hasPair) {
        float Sn = 0.f;
#pragma unroll
        for (int j = 0; j < 8; ++j) Sn += rowsum[(row + 1) * 8 + j];
        invn = 1.f / Sn; lSn = __logf(Sn);
    }

    const float* p  = fq + (size_t)row * N_GT + c * SCH;
    const float* p1 = p + N_GT;
    const float* fv = fitv + c * SCH;
    const float mean = 1.f / (float)N_GT;
    float skew = 0.f, wsum = 0.f, s5 = 0.f, kraw = 0.f;
    for (int i = threadIdx.x; i < SCH; i += 256) {
        float q0 = p[i];
        float y = __expf(q0) * inv;
        yb[i] = f2bf_rtn(y);
        float d = y - mean;
        skew += d * d * d;
        if (hasPair) {
            float q1 = p1[i];
            float y1 = __expf(q1) * invn;
            float f5 = 5.f * fv[i];
            bool m = y >= 1e-6f;
            float y1m = m ? y1 : 0.f;
            wsum += y1m;
            s5   += m ? y * __expf(f5) : 0.f;
            kraw += y1m * (q1 - lSn - q0 + lS - f5);
        }
    }
    skew = block_sum(skew, red);
    if (threadIdx.x == 0) skewS[blockIdx.x] = skew;
    if (hasPair) {
        wsum = block_sum(wsum, red);
        s5 = block_sum(s5, red);
        kraw = block_sum(kraw, red);
        if (threadIdx.x == 0) {
            pairW[c * 64 + row] = wsum;
            pairS5[c * 64 + row] = s5;
            pairKL[c * 64 + row] = kraw;
        }
    }
}

// ---------------- MFMA GEMM with global_load_lds-staged B ----------------
// partial[s][t][p] (bf16) = sum_{g in slice s} fqm[t][g] * B[g][p]
// B tile (32k x 256p fp32, 32KB) double-buffered in LDS via async
// global_load_lds dwordx4; 2 blocks/CU (64KB) -> 8 waves/CU of implicit
// overlap. (Round 6 lesson: 96KB 3-buffer counted-vmcnt at 1 block/CU
// REGRESSED 30% -- wave TLP beats explicit pipelining here.)
// Balanced split-K: slice s covers [(s*625)/16, ((s+1)*625)/16) -> 39/40.
__global__ __launch_bounds__(256, 2) void gemm_mfma_kernel(
    const float* __restrict__ B, const unsigned short* __restrict__ Abf,
    unsigned short* __restrict__ partial) {
    __shared__ __align__(16) float lds[2][KTILE][PBLK];   // 64 KB
    const int tid = threadIdx.x;
    const int l = tid & 63, w = tid >> 6;
    const int ln = l & 15, kq = l >> 4;
    const int kq8 = kq * 8;
    const int woff = w * 64;
    const int pblk = blockIdx.x * PBLK;
    const int s = blockIdx.y;

    const int ks0 = (s * KSTEPS) / NS;
    const int ks1 = ((s + 1) * KSTEPS) / NS;
    const int nk = ks1 - ks0;

    int scol = pblk + l * 4;
    if (scol > NPA - 4) scol = NPA - 4;   // last block: dup loads, stores guarded

    const unsigned short* abase = Abf + (size_t)ln * N_GT;

    f32x4 acc[4][4];
#pragma unroll
    for (int mt = 0; mt < 4; ++mt)
#pragma unroll
        for (int nt = 0; nt < 4; ++nt)
            acc[mt][nt] = (f32x4){0.f, 0.f, 0.f, 0.f};

    short8 a0[4], a1[4];

#define STAGE(BUF, KS) do {                                                    \
    const float* gsrc_ = B + (size_t)(KS) * (KTILE * NPA) + scol;              \
    _Pragma("unroll") for (int it_ = 0; it_ < 8; ++it_) {                      \
        int row_ = w * 8 + it_;                                                \
        __builtin_amdgcn_global_load_lds(                                      \
            (const __attribute__((address_space(1))) void*)(gsrc_ + (size_t)row_ * NPA), \
            (__attribute__((address_space(3))) void*)&lds[BUF][row_][0],       \
            16, 0, 0);                                                         \
    }                                                                          \
} while (0)

#define LOADA(AV, KS) do {                                                     \
    const int k0_ = (KS) * 32 + kq8;                                           \
    _Pragma("unroll") for (int mt_ = 0; mt_ < 4; ++mt_)                        \
        AV[mt_] = *(const short8*)(abase + (size_t)(mt_ * 16) * N_GT + k0_);   \
} while (0)

#define COMPUTE(BUF, AV) do {                                                  \
    f32x4 f_[8];                                                               \
    _Pragma("unroll") for (int j_ = 0; j_ < 8; ++j_)                           \
        f_[j_] = *(const f32x4*)&lds[BUF][kq8 + j_][woff + ln * 4];            \
    _Pragma("unroll") for (int nt_ = 0; nt_ < 4; ++nt_) {                      \
        short8 bb_;                                                            \
        _Pragma("unroll") for (int j_ = 0; j_ < 8; ++j_)                       \
            bb_[j_] = (short)(__float_as_uint(f_[j_][nt_]) >> 16);             \
        _Pragma("unroll") for (int mt_ = 0; mt_ < 4; ++mt_)                    \
            acc[mt_][nt_] = __builtin_amdgcn_mfma_f32_16x16x32_bf16(           \
                AV[mt_], bb_, acc[mt_][nt_], 0, 0, 0);                         \
    }                                                                          \
} while (0)

    STAGE(0, ks0);
    LOADA(a0, ks0);
    int i = 0;
    for (; i + 1 < nk; i += 2) {
        __syncthreads();                       // tile i staged & prev reads done
        STAGE(1, ks0 + i + 1);
        LOADA(a1, ks0 + i + 1);
        COMPUTE(0, a0);
        __syncthreads();                       // tile i+1 staged & reads of buf0 done
        if (i + 2 < nk) { STAGE(0, ks0 + i + 2); LOADA(a0, ks0 + i + 2); }
        COMPUTE(1, a1);
    }
    if (i < nk) {                              // odd tail (tile in buf 0)
        __syncthreads();
        COMPUTE(0, a0);
    }

#undef STAGE
#undef LOADA
#undef COMPUTE

    // epilogue: bf16 partial store (RTN); rel err 2^-9 per slice, ~0.4%
    // worst-case on the summed marginal -> log abs err ~0.004 << 0.1675
    const int rbase = kq * 4;
    const int pst = pblk + woff + ln * 4;
    unsigned short* ps = partial + (size_t)s * (N_T * NPA);
    if (pst < NPA) {
#pragma unroll
        for (int mt = 0; mt < 4; ++mt) {
#pragma unroll
            for (int r = 0; r < 4; ++r) {
                int t = mt * 16 + rbase + r;
                if (t < N_T) {
                    u16x4 v = {f2bf_rtn(acc[mt][0][r]), f2bf_rtn(acc[mt][1][r]),
                               f2bf_rtn(acc[mt][2][r]), f2bf_rtn(acc[mt][3][r])};
                    *reinterpret_cast<u16x4*>(ps + (size_t)t * NPA + pst) = v;
                }
            }
        }
    }
}

// ---------------- reduce partials + log; last block = finalize ----------------
__global__ __launch_bounds__(256) void reduce_log_kernel(
    const unsigned short* __restrict__ partial, float* __restrict__ out,
    const float* __restrict__ skewS, const float* __restrict__ pairW,
    const float* __restrict__ pairS5, const float* __restrict__ pairKL) {
    __shared__ float red[8];
    if (blockIdx.x == NRED) {            // finalize block: both scalar losses
        float sk = 0.f;
        for (int i = threadIdx.x; i < N_T * 8; i += 256) sk += skewS[i];
        sk = block_sum(sk, red);
        if (threadIdx.x == 0)
            out[400001] = sk * (-1.f / ((float)N_GT * (float)N_T));
        if (threadIdx.x < 64) {
            int t = threadIdx.x;
            float v = 0.f;
            if (t < N_T - 1) {
                float W = 0.f, S5 = 0.f, KL = 0.f;
#pragma unroll
                for (int c = 0; c < 8; ++c) {
                    W  += pairW[c * 64 + t];
                    S5 += pairS5[c * 64 + t];
                    KL += pairKL[c * 64 + t];
                }
                if (W >= 0.3f)
                    v = KL + W * (__logf(S5) - __logf(W));
            }
            v = wave_sum(v);
            if (t == 0) out[400000] = v * (1.f / (float)(N_T - 1));
        }
        return;
    }

    int i = blockIdx.x * 256 + threadIdx.x;
    if (i >= (N_T * NPA) / 4) return;
    float4 s = {0.f, 0.f, 0.f, 0.f};
#pragma unroll
    for (int k = 0; k < NS; ++k) {
        u16x4 v = *reinterpret_cast<const u16x4*>(
            partial + (size_t)k * (N_T * NPA) + (size_t)i * 4);
        s.x += __uint_as_float((unsigned)v[0] << 16);
        s.y += __uint_as_float((unsigned)v[1] << 16);
        s.z += __uint_as_float((unsigned)v[2] << 16);
        s.w += __uint_as_float((unsigned)v[3] << 16);
    }
    const float r = 1.f / (float)N_POS;
    float4 o;
    o.x = __logf(s.x * r + 1e-10f);
    o.y = __logf(s.y * r + 1e-10f);
    o.z = __logf(s.z * r + 1e-10f);
    o.w = __logf(s.w * r + 1e-10f);
    *reinterpret_cast<float4*>(out + (size_t)i * 4) = o;
}

extern "C" void kernel_launch(void* const* d_in, const int* in_sizes, int n_in,
                              void* d_out, int out_size, void* d_ws, size_t ws_size,
                              hipStream_t stream) {
    const float* fitness = (const float*)d_in[0];
    const float* fq_mat  = (const float*)d_in[1];
    const float* geno    = (const float*)d_in[2];
    float* out = (float*)d_out;

    char* ws = (char*)d_ws;
    unsigned short* fqmb    = (unsigned short*)ws;       // 64*20000*2 = 2,560,000 B
    float* rowsum           = (float*)(ws + 2560000);    // 400*4 = 1,600 B
    float* skewS            = (float*)(ws + 2561600);    // 512*4 = 2,048 B
    float* pairW            = (float*)(ws + 2563648);    // 8*64*4 = 2,048 B
    float* pairS5           = (float*)(ws + 2565696);    // 2,048 B
    float* pairKL           = (float*)(ws + 2567744);    // 2,048 B
    unsigned short* partial = (unsigned short*)(ws + 2570240); // NS*50*8000*2 = 12.8 MB

    // no memsets: every buffer consumed is deterministically written first
    hipLaunchKernelGGL(softmax_sum_kernel, dim3(N_T * 8), dim3(256), 0, stream,
                       fq_mat, rowsum);
    hipLaunchKernelGGL(softmax_write_kernel, dim3(64 * 8), dim3(256), 0, stream,
                       fq_mat, rowsum, fitness, fqmb, skewS, pairW, pairS5, pairKL);
    hipLaunchKernelGGL(gemm_mfma_kernel, dim3(NPA / PBLK + 1, NS), dim3(256), 0, stream,
                       geno, fqmb, partial);
    hipLaunchKernelGGL(reduce_log_kernel, dim3(NRED + 1), dim3(256), 0, stream,
                       partial, out, skewS, pairW, pairS5, pairKL);
}

// Round 10
// 139.207 us; speedup vs baseline: 1.4540x; 1.0008x over previous
//
#include <hip/hip_runtime.h>
#include <cfloat>
#include <cstdint>

#define N_GT 20000
#define N_T 50
#define NPA 8000          // N_POS * ALPHA
#define N_POS 2000
#define KSTEPS 625        // N_GT / 32
#define KTILE 32          // k rows per LDS tile
#define PBLK 256          // p columns per block
#define NS 16             // split-K slices (32 x 16 = 512 blocks = 2/CU)
#define SCH 2500          // softmax chunk (8 chunks per row)
#define NRED 391          // reduce blocks: ceil(100000/256)

typedef __attribute__((ext_vector_type(8))) short short8;
typedef __attribute__((ext_vector_type(4))) float f32x4;
typedef __attribute__((ext_vector_type(4))) unsigned short u16x4;

// ---------------- block reduction helpers ----------------
__device__ __forceinline__ float wave_sum(float v) {
#pragma unroll
    for (int o = 32; o > 0; o >>= 1) v += __shfl_down(v, o, 64);
    return v;
}
__device__ float block_sum(float v, float* red) {
    int lane = threadIdx.x & 63, wid = threadIdx.x >> 6, nw = blockDim.x >> 6;
    v = wave_sum(v);
    __syncthreads();
    if (lane == 0) red[wid] = v;
    __syncthreads();
    if (wid == 0) {
        float x = (lane < nw) ? red[lane] : 0.f;
        x = wave_sum(x);
        if (lane == 0) red[0] = x;
    }
    __syncthreads();
    return red[0];
}
__device__ __forceinline__ unsigned short f2bf_rtn(float x) {
    unsigned u = __float_as_uint(x);
    return (unsigned short)((u + 0x7FFFu + ((u >> 16) & 1u)) >> 16);
}

// ---------------- softmax pass 1: per-chunk sum of exp ----------------
__global__ __launch_bounds__(256) void softmax_sum_kernel(
    const float* __restrict__ fq, float* __restrict__ rowsum) {
    __shared__ float red[8];
    int row = blockIdx.x >> 3, c = blockIdx.x & 7;
    const float* p = fq + (size_t)row * N_GT + c * SCH;
    float s = 0.f;
    for (int i = threadIdx.x; i < SCH; i += 256) s += __expf(p[i]);
    s = block_sum(s, red);
    if (threadIdx.x == 0) rowsum[blockIdx.x] = s;
}

// ---------------- softmax pass 2: bf16 fqm, skew + fitness stats (slots) ----
__global__ __launch_bounds__(256) void softmax_write_kernel(
    const float* __restrict__ fq, const float* __restrict__ rowsum,
    const float* __restrict__ fitv, unsigned short* __restrict__ fqmb,
    float* __restrict__ skewS, float* __restrict__ pairW,
    float* __restrict__ pairS5, float* __restrict__ pairKL) {
    __shared__ float red[8];
    int row = blockIdx.x >> 3, c = blockIdx.x & 7;
    unsigned short* yb = fqmb + (size_t)row * N_GT + c * SCH;

    if (row >= N_T) {                    // pad rows 50..63: zero, done
        uint2* z = reinterpret_cast<uint2*>(yb);
        for (int i = threadIdx.x; i < SCH / 4; i += 256) z[i] = (uint2){0u, 0u};
        return;
    }

    float S = 0.f;
#pragma unroll
    for (int j = 0; j < 8; ++j) S += rowsum[row * 8 + j];
    float inv = 1.f / S, lS = __logf(S);
    bool hasPair = row < N_T - 1;
    float invn = 0.f, lSn = 0.f;
    if (hasPair) {
        float Sn = 0.f;
#pragma unroll
        for (int j = 0; j < 8; ++j) Sn += rowsum[(row + 1) * 8 + j];
        invn = 1.f / Sn; lSn = __logf(Sn);
    }

    const float* p  = fq + (size_t)row * N_GT + c * SCH;
    const float* p1 = p + N_GT;
    const float* fv = fitv + c * SCH;
    const float mean = 1.f / (float)N_GT;
    float skew = 0.f, wsum = 0.f, s5 = 0.f, kraw = 0.f;
    for (int i = threadIdx.x; i < SCH; i += 256) {
        float q0 = p[i];
        float y = __expf(q0) * inv;
        yb[i] = f2bf_rtn(y);
        float d = y - mean;
        skew += d * d * d;
        if (hasPair) {
            float q1 = p1[i];
            float y1 = __expf(q1) * invn;
            float f5 = 5.f * fv[i];
            bool m = y >= 1e-6f;
            float y1m = m ? y1 : 0.f;
            wsum += y1m;
            s5   += m ? y * __expf(f5) : 0.f;
            kraw += y1m * (q1 - lSn - q0 + lS - f5);
        }
    }
    skew = block_sum(skew, red);
    if (threadIdx.x == 0) skewS[blockIdx.x] = skew;
    if (hasPair) {
        wsum = block_sum(wsum, red);
        s5 = block_sum(s5, red);
        kraw = block_sum(kraw, red);
        if (threadIdx.x == 0) {
            pairW[c * 64 + row] = wsum;
            pairS5[c * 64 + row] = s5;
            pairKL[c * 64 + row] = kraw;
        }
    }
}

// ---------------- MFMA GEMM: counted-vmcnt double-buffer ----------------
// partial[s][t][p] (bf16) = sum_{g in slice s} fqm[t][g] * B[g][p]
// Round-9 shape kept EXACTLY (2 x 32KB buffers, 2 blocks/CU, 8 waves/CU);
// only the sync changed: raw s_barrier + counted s_waitcnt vmcnt(12)
// instead of __syncthreads' vmcnt(0) drain. Per iter i the VMEM queue is
// (oldest->newest) [LOADA a_cur(4), STAGE tile-i(8), LOADA a_next(4),
// STAGE tile-i+1(8)]: vmcnt(12) completes exactly a_cur+stage(i). Each
// wave waits its OWN stage then barriers -> all waves' stage(i) complete.
// Barrier A (before next stage-issue) protects LDS reuse.
__global__ __launch_bounds__(256, 2) void gemm_mfma_kernel(
    const float* __restrict__ B, const unsigned short* __restrict__ Abf,
    unsigned short* __restrict__ partial) {
    __shared__ __align__(16) float lds[2][KTILE][PBLK];   // 64 KB
    const int tid = threadIdx.x;
    const int l = tid & 63, w = tid >> 6;
    const int ln = l & 15, kq = l >> 4;
    const int kq8 = kq * 8;
    const int woff = w * 64;
    const int pblk = blockIdx.x * PBLK;
    const int s = blockIdx.y;

    const int ks0 = (s * KSTEPS) / NS;
    const int ks1 = ((s + 1) * KSTEPS) / NS;
    const int nk = ks1 - ks0;

    int scol = pblk + l * 4;
    if (scol > NPA - 4) scol = NPA - 4;   // last block: dup loads, stores guarded

    const unsigned short* abase = Abf + (size_t)ln * N_GT;

    f32x4 acc[4][4];
#pragma unroll
    for (int mt = 0; mt < 4; ++mt)
#pragma unroll
        for (int nt = 0; nt < 4; ++nt)
            acc[mt][nt] = (f32x4){0.f, 0.f, 0.f, 0.f};

    short8 a0[4], a1[4];

#define STAGE(BUF, KS) do {                                                    \
    const float* gsrc_ = B + (size_t)(KS) * (KTILE * NPA) + scol;              \
    _Pragma("unroll") for (int it_ = 0; it_ < 8; ++it_) {                      \
        int row_ = w * 8 + it_;                                                \
        __builtin_amdgcn_global_load_lds(                                      \
            (const __attribute__((address_space(1))) void*)(gsrc_ + (size_t)row_ * NPA), \
            (__attribute__((address_space(3))) void*)&lds[BUF][row_][0],       \
            16, 0, 0);                                                         \
    }                                                                          \
} while (0)

#define LOADA(AV, KS) do {                                                     \
    const int k0_ = (KS) * 32 + kq8;                                           \
    _Pragma("unroll") for (int mt_ = 0; mt_ < 4; ++mt_)                        \
        AV[mt_] = *(const short8*)(abase + (size_t)(mt_ * 16) * N_GT + k0_);   \
} while (0)

#define COMPUTE(BUF, AV) do {                                                  \
    f32x4 f_[8];                                                               \
    _Pragma("unroll") for (int j_ = 0; j_ < 8; ++j_)                           \
        f_[j_] = *(const f32x4*)&lds[BUF][kq8 + j_][woff + ln * 4];            \
    _Pragma("unroll") for (int nt_ = 0; nt_ < 4; ++nt_) {                      \
        short8 bb_;                                                            \
        _Pragma("unroll") for (int j_ = 0; j_ < 8; ++j_)                       \
            bb_[j_] = (short)(__float_as_uint(f_[j_][nt_]) >> 16);             \
        _Pragma("unroll") for (int mt_ = 0; mt_ < 4; ++mt_)                    \
            acc[mt_][nt_] = __builtin_amdgcn_mfma_f32_16x16x32_bf16(           \
                AV[mt_], bb_, acc[mt_][nt_], 0, 0, 0);                         \
    }                                                                          \
} while (0)

    STAGE(0, ks0);
    LOADA(a0, ks0);

#pragma unroll 1
    for (int i = 0; i < nk; ++i) {
        const int cur = i & 1;
        __builtin_amdgcn_s_barrier();              // A: prev COMPUTE done (LDS reuse)
        asm volatile("" ::: "memory");
        if (i + 1 < nk) {
            if (cur) LOADA(a0, ks0 + i + 1); else LOADA(a1, ks0 + i + 1);
            STAGE(cur ^ 1, ks0 + i + 1);
            asm volatile("s_waitcnt vmcnt(12)" ::: "memory");  // own stage(i)+a_cur done
        } else {
            asm volatile("s_waitcnt vmcnt(0)" ::: "memory");   // tail: drain
        }
        __builtin_amdgcn_s_barrier();              // B: ALL waves' stage(i) complete
        asm volatile("" ::: "memory");
        if (cur) COMPUTE(1, a1); else COMPUTE(0, a0);
    }

#undef STAGE
#undef LOADA
#undef COMPUTE

    // epilogue: bf16 partial store (RTN); rel err 2^-9 per slice, ~0.4%
    // worst-case on summed marginal -> log abs err ~0.004 << 0.1675
    const int rbase = kq * 4;
    const int pst = pblk + woff + ln * 4;
    unsigned short* ps = partial + (size_t)s * (N_T * NPA);
    if (pst < NPA) {
#pragma unroll
        for (int mt = 0; mt < 4; ++mt) {
#pragma unroll
            for (int r = 0; r < 4; ++r) {
                int t = mt * 16 + rbase + r;
                if (t < N_T) {
                    u16x4 v = {f2bf_rtn(acc[mt][0][r]), f2bf_rtn(acc[mt][1][r]),
                               f2bf_rtn(acc[mt][2][r]), f2bf_rtn(acc[mt][3][r])};
                    *reinterpret_cast<u16x4*>(ps + (size_t)t * NPA + pst) = v;
                }
            }
        }
    }
}

// ---------------- reduce partials + log; last block = finalize ----------------
__global__ __launch_bounds__(256) void reduce_log_kernel(
    const unsigned short* __restrict__ partial, float* __restrict__ out,
    const float* __restrict__ skewS, const float* __restrict__ pairW,
    const float* __restrict__ pairS5, const float* __restrict__ pairKL) {
    __shared__ float red[8];
    if (blockIdx.x == NRED) {            // finalize block: both scalar losses
        float sk = 0.f;
        for (int i = threadIdx.x; i < N_T * 8; i += 256) sk += skewS[i];
        sk = block_sum(sk, red);
        if (threadIdx.x == 0)
            out[400001] = sk * (-1.f / ((float)N_GT * (float)N_T));
        if (threadIdx.x < 64) {
            int t = threadIdx.x;
            float v = 0.f;
            if (t < N_T - 1) {
                float W = 0.f, S5 = 0.f, KL = 0.f;
#pragma unroll
                for (int c = 0; c < 8; ++c) {
                    W  += pairW[c * 64 + t];
                    S5 += pairS5[c * 64 + t];
                    KL += pairKL[c * 64 + t];
                }
                if (W >= 0.3f)
                    v = KL + W * (__logf(S5) - __logf(W));
            }
            v = wave_sum(v);
            if (t == 0) out[400000] = v * (1.f / (float)(N_T - 1));
        }
        return;
    }

    int i = blockIdx.x * 256 + threadIdx.x;
    if (i >= (N_T * NPA) / 4) return;
    float4 s = {0.f, 0.f, 0.f, 0.f};
#pragma unroll
    for (int k = 0; k < NS; ++k) {
        u16x4 v = *reinterpret_cast<const u16x4*>(
            partial + (size_t)k * (N_T * NPA) + (size_t)i * 4);
        s.x += __uint_as_float((unsigned)v[0] << 16);
        s.y += __uint_as_float((unsigned)v[1] << 16);
        s.z += __uint_as_float((unsigned)v[2] << 16);
        s.w += __uint_as_float((unsigned)v[3] << 16);
    }
    const float r = 1.f / (float)N_POS;
    float4 o;
    o.x = __logf(s.x * r + 1e-10f);
    o.y = __logf(s.y * r + 1e-10f);
    o.z = __logf(s.z * r + 1e-10f);
    o.w = __logf(s.w * r + 1e-10f);
    *reinterpret_cast<float4*>(out + (size_t)i * 4) = o;
}

extern "C" void kernel_launch(void* const* d_in, const int* in_sizes, int n_in,
                              void* d_out, int out_size, void* d_ws, size_t ws_size,
                              hipStream_t stream) {
    const float* fitness = (const float*)d_in[0];
    const float* fq_mat  = (const float*)d_in[1];
    const float* geno    = (const float*)d_in[2];
    float* out = (float*)d_out;

    char* ws = (char*)d_ws;
    unsigned short* fqmb    = (unsigned short*)ws;       // 64*20000*2 = 2,560,000 B
    float* rowsum           = (float*)(ws + 2560000);    // 400*4 = 1,600 B
    float* skewS            = (float*)(ws + 2561600);    // 512*4 = 2,048 B
    float* pairW            = (float*)(ws + 2563648);    // 8*64*4 = 2,048 B
    float* pairS5           = (float*)(ws + 2565696);    // 2,048 B
    float* pairKL           = (float*)(ws + 2567744);    // 2,048 B
    unsigned short* partial = (unsigned short*)(ws + 2570240); // NS*50*8000*2 = 12.8 MB

    // no memsets: every buffer consumed is deterministically written first
    hipLaunchKernelGGL(softmax_sum_kernel, dim3(N_T * 8), dim3(256), 0, stream,
                       fq_mat, rowsum);
    hipLaunchKernelGGL(softmax_write_kernel, dim3(64 * 8), dim3(256), 0, stream,
                       fq_mat, rowsum, fitness, fqmb, skewS, pairW, pairS5, pairKL);
    hipLaunchKernelGGL(gemm_mfma_kernel, dim3(NPA / PBLK + 1, NS), dim3(256), 0, stream,
                       geno, fqmb, partial);
    hipLaunchKernelGGL(reduce_log_kernel, dim3(NRED + 1), dim3(256), 0, stream,
                       partial, out, skewS, pairW, pairS5, pairKL);
}